// Round 6
// baseline (774.878 us; speedup 1.0000x reference)
//
#include <hip/hip_runtime.h>
#include <math.h>

#define BATCH 8
typedef unsigned short US;

typedef __attribute__((ext_vector_type(8))) short short8;
typedef __attribute__((ext_vector_type(4))) float f32x4;

__device__ __forceinline__ US f2b(float f) {
  union { float f; unsigned u; } v; v.f = f;
  unsigned r = v.u + 0x7fffu + ((v.u >> 16) & 1u);
  return (US)(r >> 16);
}
__device__ __forceinline__ float b2f(US h) {
  union { unsigned u; float f; } v; v.u = ((unsigned)h) << 16;
  return v.f;
}

__device__ __forceinline__ void gload16(const US* g, US* l) {
  __builtin_amdgcn_global_load_lds(
      (const __attribute__((address_space(1))) unsigned int*)g,
      (__attribute__((address_space(3))) unsigned int*)l, 16, 0, 0);
}

// LDS tile [rows][64] linear, XOR swizzle: 16B-cell index ^= (row&7). (128^2 kernel)
__device__ __forceinline__ int lidx2(int r, int ko) {
  return r * 64 + ((((ko >> 3) ^ (r & 7)) << 3));
}

// ================= 128^2 1-phase MFMA GEMM (fallback; verified r3-r5) ========
// C = act(A@B + bias). A bf16 phys [M][lda], B bf16 phys [N][K].
// OUT: 0=bf16 [M][N], 1=bf16 [N][M], 2=f32 [M][N], 3=dual bf16 [M][N]+[N][M].
template <int TN, int ACT, int OUT, bool HASBIAS>
__global__ __launch_bounds__(256) void mm_k(
    const US* __restrict__ A, const US* __restrict__ B,
    const float* __restrict__ bias, void* __restrict__ Cv, void* __restrict__ Cv2,
    int M, int N, int K, int lda, long long sA, long long sB, long long sC,
    long long sC2, int gx, int gy) {
  constexpr int JF = TN / 32;
  __shared__ US As[128 * 64];
  __shared__ US Bs[TN * 64];

  const int nb = blockIdx.x;
  const int nb2 = (nb & 7) * (gx * gy) + (nb >> 3);
  const int bx = nb2 % gx;
  const int by = (nb2 / gx) % gy;
  const int b = nb2 / (gx * gy);

  A += (long long)b * sA;
  B += (long long)b * sB;
  const int m0 = by * 128, n0 = bx * TN;
  const int t = threadIdx.x, lane = t & 63, w = t >> 6;
  const int wm = (w >> 1) * 64, wn = (w & 1) * (TN / 2);
  const int l15 = lane & 15, lg = lane >> 4;
  const int lrow = lane >> 3;
  const int gcell = (((lane & 7) ^ lrow) << 3);

  f32x4 acc[4][JF];
#pragma unroll
  for (int i = 0; i < 4; ++i)
#pragma unroll
    for (int j = 0; j < JF; ++j) acc[i][j] = (f32x4){0.f, 0.f, 0.f, 0.f};

  for (int k0 = 0; k0 < K; k0 += 64) {
#pragma unroll
    for (int i = 0; i < 4; ++i) {
      const int g = w * 4 + i;
      gload16(A + (long long)(m0 + g * 8 + lrow) * lda + k0 + gcell, &As[g * 512]);
    }
#pragma unroll
    for (int i = 0; i < TN / 32; ++i) {
      const int g = w * (TN / 32) + i;
      gload16(B + (long long)(n0 + g * 8 + lrow) * K + k0 + gcell, &Bs[g * 512]);
    }
    __syncthreads();

#pragma unroll
    for (int kk = 0; kk < 2; ++kk) {
      const int ko = kk * 32 + lg * 8;
      short8 af[4], bf[JF];
#pragma unroll
      for (int i = 0; i < 4; ++i)
        af[i] = *(const short8*)&As[lidx2(wm + i * 16 + l15, ko)];
#pragma unroll
      for (int j = 0; j < JF; ++j)
        bf[j] = *(const short8*)&Bs[lidx2(wn + j * 16 + l15, ko)];
#pragma unroll
      for (int i = 0; i < 4; ++i)
#pragma unroll
        for (int j = 0; j < JF; ++j)
          acc[i][j] = __builtin_amdgcn_mfma_f32_16x16x32_bf16(af[i], bf[j],
                                                              acc[i][j], 0, 0, 0);
    }
    __syncthreads();
  }

  const long long cb = (long long)b * sC;
  const long long cb2 = (long long)b * sC2;
#pragma unroll
  for (int fj = 0; fj < JF; ++fj) {
    const int col = n0 + wn + fj * 16 + l15;
    const float bsv = HASBIAS ? bias[col] : 0.0f;
#pragma unroll
    for (int fi = 0; fi < 4; ++fi) {
      const int row0 = m0 + wm + fi * 16 + lg * 4;
      float v[4];
#pragma unroll
      for (int e = 0; e < 4; ++e) {
        float x = acc[fi][fj][e] + bsv;
        if (ACT == 1) x = fmaxf(x, 0.0f);
        if (ACT == 2) x = (x > 20.0f) ? x : log1pf(expf(x));
        v[e] = x;
      }
      if (OUT == 1 || OUT == 3) {
        ushort4 pk;
        pk.x = f2b(v[0]); pk.y = f2b(v[1]); pk.z = f2b(v[2]); pk.w = f2b(v[3]);
        US* c2 = (OUT == 3) ? (US*)Cv2 : (US*)Cv;
        *(ushort4*)&c2[cb2 + (long long)col * M + row0] = pk;
      }
      if (OUT == 0 || OUT == 3) {
#pragma unroll
        for (int e = 0; e < 4; ++e)
          ((US*)Cv)[cb + (long long)(row0 + e) * N + col] = f2b(v[e]);
      }
      if (OUT == 2) {
#pragma unroll
        for (int e = 0; e < 4; ++e)
          ((float*)Cv)[cb + (long long)(row0 + e) * N + col] = v[e];
      }
    }
  }
}

// ================= 256^2 8-phase deep-pipelined MFMA GEMM ====================
// A bf16 [M][lda], B bf16 [N][K]. M%256==0, N%256==0, K%64==0, K>=128.
// OUT: 0=bf16 [M][N], 1=bf16 [N][M], 3=dual.
// LDS: 8 regions x 16KB: region = ab*4 + (tile&1)*2 + kk, layout [256 rows][32 k]
// with 16B-cell swizzle c ^= (r>>1)&3 (2-way bank access = free; gload_lds keeps
// linear dest, source k-chunk pre-swizzled).  Half-tile order per K-tile s:
// H=4s+{Ak0,Bk0,Ak1,Bk1}.  Phase p (=4t+q) computes quadrant q (kk=q>>1,
// qn=q&1) of tile t and stages H=p+6 (2 gloads); steady vmcnt(6); drain 4->0.
template <int OUT>
__global__ __launch_bounds__(512, 1) void mm256_k(
    const US* __restrict__ A, const US* __restrict__ B, void* __restrict__ Cv,
    void* __restrict__ Cv2, int M, int N, int K, int lda, long long sA,
    long long sB, long long sC, long long sC2, int gx, int gy) {
  __shared__ US lds[8][8192];

  const int nb = blockIdx.x;
  const int chunk = gx * gy;
  const int nb2 = (nb & 7) * chunk + (nb >> 3);
  const int bx = nb2 % gx;
  const int by = (nb2 / gx) % gy;
  const int b = nb2 / chunk;

  const int m0 = by * 256, n0 = bx * 256;
  const int tid = threadIdx.x;
  const int lane = tid & 63, w = tid >> 6;
  const int wr = w >> 2, wc = w & 3;      // 2 x 4 wave grid
  const int l15 = lane & 15, lg = lane >> 4;

  const US* Ab = A + (long long)b * sA + (long long)m0 * lda;
  const US* Bb = B + (long long)b * sB + (long long)n0 * K;
  const int NT = K >> 6;

  auto stageH = [&](int H) {
    const int s = H >> 2, h = H & 3;
    const int ab = h & 1, kk = h >> 1;
    US* reg = &lds[ab * 4 + (s & 1) * 2 + kk][0];
    const US* src = ab ? Bb : Ab;
    const int ld = ab ? K : lda;
#pragma unroll
    for (int i = 0; i < 2; ++i) {
      const int rbase = (w * 2 + i) * 16;
      const int r = rbase + (lane >> 2);
      const int csrc = (lane & 3) ^ ((r >> 1) & 3);
      gload16(src + (long long)r * ld + s * 64 + kk * 32 + csrc * 8,
              reg + rbase * 32);
    }
  };

  f32x4 acc[8][4];
#pragma unroll
  for (int m = 0; m < 8; ++m)
#pragma unroll
    for (int j = 0; j < 4; ++j) acc[m][j] = (f32x4){0.f, 0.f, 0.f, 0.f};
  short8 a[8];

  // prologue: tiles 0 + half of 1 (H0..H5); tile0 fully landed, H4/H5 in flight
  for (int H = 0; H < 6; ++H) stageH(H);
  asm volatile("s_waitcnt vmcnt(4)" ::: "memory");
  __builtin_amdgcn_s_barrier();

#define MMPHASE(q, VMN, DOST, tt)                                              \
  {                                                                            \
    const int kk_ = (q) >> 1, qn_ = (q) & 1;                                   \
    const US* Ar = &lds[((tt) & 1) * 2 + kk_][0];                              \
    const US* Br = &lds[4 + ((tt) & 1) * 2 + kk_][0];                          \
    if (((q) & 1) == 0) {                                                      \
      _Pragma("unroll") for (int m = 0; m < 8; ++m) {                          \
        const int r = wr * 128 + m * 16 + l15;                                 \
        a[m] = *(const short8*)&Ar[r * 32 + ((lg ^ ((r >> 1) & 3)) << 3)];     \
      }                                                                        \
    }                                                                          \
    short8 bfr0, bfr1;                                                         \
    {                                                                          \
      const int r0_ = wc * 64 + qn_ * 32 + l15;                                \
      bfr0 = *(const short8*)&Br[r0_ * 32 + ((lg ^ ((r0_ >> 1) & 3)) << 3)];   \
      const int r1_ = r0_ + 16;                                                \
      bfr1 = *(const short8*)&Br[r1_ * 32 + ((lg ^ ((r1_ >> 1) & 3)) << 3)];   \
    }                                                                          \
    if (DOST) stageH(4 * (tt) + (q) + 6);                                      \
    asm volatile("s_waitcnt vmcnt(" #VMN ")" ::: "memory");                    \
    __builtin_amdgcn_s_barrier();                                              \
    __builtin_amdgcn_sched_barrier(0);                                         \
    __builtin_amdgcn_s_setprio(1);                                             \
    _Pragma("unroll") for (int m = 0; m < 8; ++m) {                            \
      acc[m][qn_ * 2 + 0] = __builtin_amdgcn_mfma_f32_16x16x32_bf16(           \
          a[m], bfr0, acc[m][qn_ * 2 + 0], 0, 0, 0);                           \
      acc[m][qn_ * 2 + 1] = __builtin_amdgcn_mfma_f32_16x16x32_bf16(           \
          a[m], bfr1, acc[m][qn_ * 2 + 1], 0, 0, 0);                           \
    }                                                                          \
    __builtin_amdgcn_s_setprio(0);                                             \
    __builtin_amdgcn_s_barrier();                                              \
    __builtin_amdgcn_sched_barrier(0);                                         \
  }

  int t2 = 0;
  for (; t2 < NT - 2; ++t2) {
    MMPHASE(0, 6, true, t2)
    MMPHASE(1, 6, true, t2)
    MMPHASE(2, 6, true, t2)
    MMPHASE(3, 6, true, t2)
  }
  MMPHASE(0, 6, true, NT - 2)
  MMPHASE(1, 6, true, NT - 2)
  MMPHASE(2, 6, false, NT - 2)
  MMPHASE(3, 4, false, NT - 2)
  MMPHASE(0, 4, false, NT - 1)
  MMPHASE(1, 0, false, NT - 1)
  MMPHASE(2, 0, false, NT - 1)
  MMPHASE(3, 0, false, NT - 1)
#undef MMPHASE

  const long long cb = (long long)b * sC;
  const long long cb2 = (long long)b * sC2;
#pragma unroll
  for (int j = 0; j < 4; ++j) {
    const int col = n0 + wc * 64 + j * 16 + l15;
#pragma unroll
    for (int m = 0; m < 8; ++m) {
      const int row0 = m0 + wr * 128 + m * 16 + lg * 4;
      if (OUT == 1 || OUT == 3) {
        ushort4 pk;
        pk.x = f2b(acc[m][j][0]); pk.y = f2b(acc[m][j][1]);
        pk.z = f2b(acc[m][j][2]); pk.w = f2b(acc[m][j][3]);
        US* c2 = (OUT == 3) ? (US*)Cv2 : (US*)Cv;
        *(ushort4*)&c2[cb2 + (long long)col * M + row0] = pk;
      }
      if (OUT == 0 || OUT == 3) {
#pragma unroll
        for (int e = 0; e < 4; ++e)
          ((US*)Cv)[cb + (long long)(row0 + e) * N + col] = f2b(acc[m][j][e]);
      }
    }
  }
}

// ---------------- split column softmax over R of x [B][R][C] ----------------
template <int RPT>
__global__ __launch_bounds__(256) void sm_partial_k(
    const US* __restrict__ x, float* __restrict__ pm, float* __restrict__ ps,
    int R, int C, long long sB, int NS) {
  const int b = blockIdx.y, blk = blockIdx.x;
  const int cpr = C >> 3;
  const int t = threadIdx.x;
  const int cslot = t & (cpr - 1);
  const int rsub = t / cpr;
  const int nsub = 256 / cpr;
  const int rowsPerBlock = R / NS;
  const int r0 = blk * rowsPerBlock + rsub * RPT;
  const US* p = x + (long long)b * sB + (long long)r0 * C + cslot * 8;
  union { uint4 v; US s[8]; } buf[RPT];
#pragma unroll
  for (int i = 0; i < RPT; ++i) buf[i].v = *(const uint4*)(p + (long long)i * C);
  float M[8], S[8];
#pragma unroll
  for (int j = 0; j < 8; ++j) M[j] = b2f(buf[0].s[j]);
#pragma unroll
  for (int i = 1; i < RPT; ++i)
#pragma unroll
    for (int j = 0; j < 8; ++j) M[j] = fmaxf(M[j], b2f(buf[i].s[j]));
#pragma unroll
  for (int j = 0; j < 8; ++j) S[j] = 0.f;
#pragma unroll
  for (int i = 0; i < RPT; ++i)
#pragma unroll
    for (int j = 0; j < 8; ++j) S[j] += __expf(b2f(buf[i].s[j]) - M[j]);
  const long long pi = (long long)(b * NS + blk) * nsub + rsub;
  float* pmo = pm + pi * C + cslot * 8;
  float* pso = ps + pi * C + cslot * 8;
  *(float4*)pmo = make_float4(M[0], M[1], M[2], M[3]);
  *(float4*)(pmo + 4) = make_float4(M[4], M[5], M[6], M[7]);
  *(float4*)pso = make_float4(S[0], S[1], S[2], S[3]);
  *(float4*)(pso + 4) = make_float4(S[4], S[5], S[6], S[7]);
}

__global__ __launch_bounds__(256) void sm_combine_k(
    const float* __restrict__ pm, const float* __restrict__ ps,
    float* __restrict__ Mf, float* __restrict__ Sinv, int C, int NP) {
  const int b = blockIdx.x, t = threadIdx.x;
  const int cpr = C >> 3;
  if (t >= cpr) return;
  const int c = t * 8;
  const float* pmB = pm + (long long)b * NP * C + c;
  const float* psB = ps + (long long)b * NP * C + c;
  float M[8], S[8];
#pragma unroll
  for (int j = 0; j < 8; ++j) { M[j] = pmB[j]; S[j] = psB[j]; }
  for (int e = 1; e < NP; ++e) {
    const float* pme = pmB + (long long)e * C;
    const float* pse = psB + (long long)e * C;
#pragma unroll
    for (int j = 0; j < 8; ++j) {
      const float m2 = pme[j], s2 = pse[j];
      const float nm = fmaxf(M[j], m2);
      S[j] = S[j] * __expf(M[j] - nm) + s2 * __expf(m2 - nm);
      M[j] = nm;
    }
  }
#pragma unroll
  for (int j = 0; j < 8; ++j) {
    Mf[(long long)b * C + c + j] = M[j];
    Sinv[(long long)b * C + c + j] = 1.0f / S[j];
  }
}

template <int RPT>
__global__ __launch_bounds__(256) void sm_norm_k(
    US* __restrict__ x, const float* __restrict__ Mf,
    const float* __restrict__ Sinv, int R, int C, long long sB, int NS) {
  const int b = blockIdx.y, blk = blockIdx.x;
  const int cpr = C >> 3;
  const int t = threadIdx.x;
  const int cslot = t & (cpr - 1);
  const int rsub = t / cpr;
  const int rowsPerBlock = R / NS;
  const int r0 = blk * rowsPerBlock + rsub * RPT;
  US* p = x + (long long)b * sB + (long long)r0 * C + cslot * 8;
  float M[8], Si[8];
#pragma unroll
  for (int j = 0; j < 8; ++j) {
    M[j] = Mf[(long long)b * C + cslot * 8 + j];
    Si[j] = Sinv[(long long)b * C + cslot * 8 + j];
  }
#pragma unroll
  for (int i = 0; i < RPT; ++i) {
    union { uint4 v; US s[8]; } buf;
    buf.v = *(const uint4*)(p + (long long)i * C);
#pragma unroll
    for (int j = 0; j < 8; ++j)
      buf.s[j] = f2b(__expf(b2f(buf.s[j]) - M[j]) * Si[j]);
    *(uint4*)(p + (long long)i * C) = buf.v;
  }
}

// ---------------- f32 transpose -> bf16: [B][R][C] -> [B][C][R] ----
__global__ __launch_bounds__(256) void trans_k(const float* __restrict__ src,
                                               US* __restrict__ dst, int R, int C,
                                               long long sIn, long long sOut) {
  __shared__ US L[64][65];
  const int b = blockIdx.z;
  const int r0 = blockIdx.y * 64, c0 = blockIdx.x * 64;
  const int t = threadIdx.x;
  const int lr = t >> 4, lc = (t & 15) * 4;
  const float* s = src + (long long)b * sIn;
#pragma unroll
  for (int i = 0; i < 4; ++i) {
    const int rr = r0 + lr + 16 * i;
    const float4 v = *(const float4*)&s[(long long)rr * C + c0 + lc];
    L[lr + 16 * i][lc + 0] = f2b(v.x);
    L[lr + 16 * i][lc + 1] = f2b(v.y);
    L[lr + 16 * i][lc + 2] = f2b(v.z);
    L[lr + 16 * i][lc + 3] = f2b(v.w);
  }
  __syncthreads();
#pragma unroll
  for (int i = 0; i < 4; ++i) {
    ushort4 o;
    o.x = L[lc + 0][lr + 16 * i];
    o.y = L[lc + 1][lr + 16 * i];
    o.z = L[lc + 2][lr + 16 * i];
    o.w = L[lc + 3][lr + 16 * i];
    *(ushort4*)&dst[(long long)b * sOut + (long long)(c0 + lr + 16 * i) * R + r0 + lc] = o;
  }
}

// ---------------- fused weight transposes ----------------
struct WT { const float* src; US* dst; int R, C, tileOff; };
struct WTab { WT e[11]; };

__global__ __launch_bounds__(256) void wtrans_k(WTab tab) {
  __shared__ US L[64][65];
  const int tile = blockIdx.x;
  int i = 0;
#pragma unroll
  for (int j = 1; j < 11; ++j)
    if (tab.e[j].tileOff <= tile) i = j;
  const WT w = tab.e[i];
  const int lt = tile - w.tileOff;
  const int tc = w.C / 64;
  const int r0 = (lt / tc) * 64, c0 = (lt % tc) * 64;
  const int t = threadIdx.x;
  const int lr = t >> 4, lc = (t & 15) * 4;
#pragma unroll
  for (int k = 0; k < 4; ++k) {
    const int rr = r0 + lr + 16 * k;
    const float4 v = *(const float4*)&w.src[(long long)rr * w.C + c0 + lc];
    L[lr + 16 * k][lc + 0] = f2b(v.x);
    L[lr + 16 * k][lc + 1] = f2b(v.y);
    L[lr + 16 * k][lc + 2] = f2b(v.z);
    L[lr + 16 * k][lc + 3] = f2b(v.w);
  }
  __syncthreads();
#pragma unroll
  for (int k = 0; k < 4; ++k) {
    ushort4 o;
    o.x = L[lc + 0][lr + 16 * k];
    o.y = L[lc + 1][lr + 16 * k];
    o.z = L[lc + 2][lr + 16 * k];
    o.w = L[lc + 3][lr + 16 * k];
    *(ushort4*)&w.dst[(long long)(c0 + lr + 16 * k) * w.R + r0 + lc] = o;
  }
}

// ---------------- f32 -> bf16 ----------------
__global__ __launch_bounds__(256) void f2b_k(const float* __restrict__ s,
                                             US* __restrict__ d, int n4) {
  const int i = blockIdx.x * 256 + threadIdx.x;
  if (i < n4) {
    const float4 v = ((const float4*)s)[i];
    ushort4 o;
    o.x = f2b(v.x); o.y = f2b(v.y); o.z = f2b(v.z); o.w = f2b(v.w);
    ((ushort4*)d)[i] = o;
  }
}

// ---------------- reparameterize ----------------
__global__ __launch_bounds__(256) void reparam_k(
    const float* __restrict__ h3, const float* __restrict__ eps,
    float* __restrict__ om, float* __restrict__ olv, US* __restrict__ z,
    int total) {
  const int i = blockIdx.x * 256 + threadIdx.x;
  if (i >= total) return;
  const int j = i & 63;
  const long long r = i >> 6;
  const float m = h3[r * 128 + j];
  const float lv = h3[r * 128 + 64 + j];
  om[i] = m;
  olv[i] = lv;
  z[i] = f2b(m + expf(0.5f * lv) * eps[i]);
}

// ---------------- host dispatch ----------------
static void mm(hipStream_t st, const US* A, const US* B, const float* bias,
               void* C, void* C2, int M, int N, int K, int lda, long long sA,
               long long sB, long long sC, long long sC2, int act, int outm,
               int tn) {
  const int gx = N / tn, gy = M / 128;
  dim3 g(gx * gy * BATCH), blk(256);
#define L(TN, ACT, OUT, HB) \
  mm_k<TN, ACT, OUT, HB><<<g, blk, 0, st>>>(A, B, bias, C, C2, M, N, K, lda, sA, sB, sC, sC2, gx, gy)
  if (tn == 64) {
    if (outm == 0) L(64, 0, 0, false);
    else if (outm == 1) L(64, 0, 1, false);
    else L(64, 2, 2, true);            // final output: softplus + bias, f32
  } else {
    if (outm == 0) {
      if (act == 1) L(128, 1, 0, true);
      else L(128, 0, 0, false);
    } else if (outm == 1) {
      if (act == 1) L(128, 1, 1, true);
      else L(128, 0, 1, false);
    } else if (outm == 2) L(128, 0, 2, true);
    else L(128, 0, 3, false);          // dual
  }
#undef L
}

static void mm256(hipStream_t st, const US* A, const US* B, void* C, void* C2,
                  int M, int N, int K, int lda, long long sA, long long sB,
                  long long sC, long long sC2, int outm) {
  const int gx = N / 256, gy = M / 256;
  dim3 g(gx * gy * BATCH), blk(512);
  if (outm == 0)
    mm256_k<0><<<g, blk, 0, st>>>(A, B, C, C2, M, N, K, lda, sA, sB, sC, sC2, gx, gy);
  else if (outm == 1)
    mm256_k<1><<<g, blk, 0, st>>>(A, B, C, C2, M, N, K, lda, sA, sB, sC, sC2, gx, gy);
  else
    mm256_k<3><<<g, blk, 0, st>>>(A, B, C, C2, M, N, K, lda, sA, sB, sC, sC2, gx, gy);
}

extern "C" void kernel_launch(void* const* d_in, const int* in_sizes, int n_in,
                              void* d_out, int out_size, void* d_ws, size_t ws_size,
                              hipStream_t stream) {
  const float* x      = (const float*)d_in[0];
  const float* eps    = (const float*)d_in[1];
  const float* adj    = (const float*)d_in[2];
  const float* We1    = (const float*)d_in[3];
  const float* be1    = (const float*)d_in[4];
  const float* Kemb1  = (const float*)d_in[5];
  const float* Kpool1 = (const float*)d_in[6];
  const float* We2    = (const float*)d_in[7];
  const float* be2    = (const float*)d_in[8];
  const float* Kemb2  = (const float*)d_in[9];
  const float* Kpool2 = (const float*)d_in[10];
  const float* We3    = (const float*)d_in[11];
  const float* be3    = (const float*)d_in[12];
  const float* Wd0    = (const float*)d_in[13];
  const float* bd0    = (const float*)d_in[14];
  const float* Wd1    = (const float*)d_in[15];
  const float* bd1    = (const float*)d_in[16];
  const float* Wd2    = (const float*)d_in[17];
  const float* bd2    = (const float*)d_in[18];
  const float* Wdf    = (const float*)d_in[19];
  const float* bdf    = (const float*)d_in[20];
  (void)in_sizes; (void)n_in; (void)ws_size; (void)out_size;

  float* out = (float*)d_out;
  float* out_mean = out + (long long)8 * 2048 * 64;
  float* out_lv = out_mean + (long long)8 * 512 * 64;

  char* base = (char*)d_ws;
  size_t off = 0;
  auto alloc = [&](size_t bytes) {
    char* p = base + off;
    off += (bytes + 255) & ~(size_t)255;
    return p;
  };
  US* adjb = (US*)alloc(2048LL * 2048 * 2);
  US* xT   = (US*)alloc(8LL * 64 * 2048 * 2);
  US* Y0   = (US*)alloc(8LL * 2048 * 64 * 2);
  US* h1T  = (US*)alloc(8LL * 256 * 2048 * 2);
  US* g1   = (US*)alloc(8LL * 2048 * 256 * 2);
  // stage-1 region: per batch rows [s1T(1024) | z1T(256) | AS1T(1024)] x 2048
  US* R1   = (US*)alloc(8LL * 2304 * 2048 * 2);
  US* AS1  = (US*)alloc(8LL * 2048 * 1024 * 2);
  US* P1o  = (US*)alloc(8LL * 1024 * 1280 * 2);   // [xp1(256c) | A1(1024c)]
  US* t1T  = (US*)alloc(8LL * 256 * 1024 * 2);
  US* h2T  = (US*)alloc(8LL * 256 * 1024 * 2);
  US* g2   = (US*)alloc(8LL * 1024 * 256 * 2);
  // stage-2 region: per batch rows [s2T(512) | z2T(256) | AS2T(512)] x 1024
  US* R2   = (US*)alloc(8LL * 1280 * 1024 * 2);
  US* AS2  = (US*)alloc(8LL * 1024 * 512 * 2);
  US* P2o  = (US*)alloc(8LL * 512 * 768 * 2);     // [xp2(256c) | A2(512c)]
  US* t2T  = (US*)alloc(8LL * 128 * 512 * 2);
  float* h3f = (float*)alloc(8LL * 512 * 128 * 4);
  US* zlb  = (US*)alloc(8LL * 512 * 64 * 2);
  US* t3T  = (US*)alloc(8LL * 256 * 512 * 2);
  US* d0   = (US*)alloc(8LL * 512 * 256 * 2);
  US* t4T  = (US*)alloc(8LL * 256 * 512 * 2);
  US* d2   = (US*)alloc(8LL * 1024 * 256 * 2);
  US* t5T  = (US*)alloc(8LL * 256 * 1024 * 2);
  US* d4   = (US*)alloc(8LL * 2048 * 256 * 2);
  US* t6T  = (US*)alloc(8LL * 64 * 2048 * 2);
  float* pm   = (float*)alloc(8LL * 128 * 2048 * 4);
  float* ps   = (float*)alloc(8LL * 128 * 2048 * 4);
  float* Mf   = (float*)alloc(8LL * 2048 * 4);
  float* Sinv = (float*)alloc(8LL * 2048 * 4);
  US* We1T  = (US*)alloc(256 * 64 * 2);
  US* KpKe1 = (US*)alloc(1280 * 256 * 2);   // [Kpool1^T(1024r) | Kemb1^T(256r)]
  US* We2T  = (US*)alloc(256 * 256 * 2);
  US* KpKe2 = (US*)alloc(768 * 256 * 2);    // [Kpool2^T(512r) | Kemb2^T(256r)]
  US* We3T  = (US*)alloc(128 * 256 * 2);
  US* Wd0T  = (US*)alloc(256 * 64 * 2);
  US* Wd1T  = (US*)alloc(256 * 256 * 2);
  US* Wd2T  = (US*)alloc(256 * 256 * 2);
  US* WdfT  = (US*)alloc(64 * 256 * 2);

  // ---- input conversions ----
  f2b_k<<<dim3(2048 * 2048 / 4 / 256), dim3(256), 0, stream>>>(adj, adjb, 2048 * 2048 / 4);
  trans_k<<<dim3(1, 32, 8), dim3(256), 0, stream>>>(x, xT, 2048, 64, 2048LL * 64,
                                                    64LL * 2048);
  {
    WTab tab;
    int toff = 0, i = 0;
    auto add = [&](const float* s, US* d, int R, int C) {
      tab.e[i++] = WT{s, d, R, C, toff};
      toff += (R / 64) * (C / 64);
    };
    add(We1, We1T, 64, 256);
    add(Kpool1, KpKe1, 256, 1024);
    add(Kemb1, KpKe1 + 1024 * 256, 256, 256);
    add(We2, We2T, 256, 256);
    add(Kpool2, KpKe2, 256, 512);
    add(Kemb2, KpKe2 + 512 * 256, 256, 256);
    add(We3, We3T, 256, 128);
    add(Wd0, Wd0T, 64, 256);
    add(Wd1, Wd1T, 256, 256);
    add(Wd2, Wd2T, 256, 256);
    add(Wdf, WdfT, 256, 64);
    wtrans_k<<<dim3(toff), dim3(256), 0, stream>>>(tab);
  }

  const long long SR1 = 2304LL * 2048, SR2 = 1280LL * 1024;
  US* s1T  = R1;                     // [1024][2048] per batch
  US* B1   = R1 + 1024 * 2048;       // rows [z1T(256) | AS1T(1024)]
  US* AS1T = R1 + 1280 * 2048;
  US* s2T  = R2;                     // [512][1024] per batch
  US* B2   = R2 + 512 * 1024;        // rows [z2T(256) | AS2T(512)]
  US* AS2T = R2 + 768 * 1024;
  US* A1c  = P1o + 256;              // A1 = cols 256.. of P1o, lda=1280
  US* A2c  = P2o + 256;              // A2 = cols 256.. of P2o, lda=768

  // ---------------- encode ----------------
  mm(stream, adjb, xT, nullptr, Y0, nullptr, 2048, 64, 2048, 2048, 0, 64LL * 2048,
     2048LL * 64, 0, 0, 0, 64);
  mm(stream, Y0, We1T, be1, h1T, nullptr, 2048, 256, 64, 64, 2048LL * 64, 0, 0,
     256LL * 2048, 1, 1, 128);
  mm(stream, adjb, h1T, nullptr, g1, nullptr, 2048, 256, 2048, 2048, 0,
     256LL * 2048, 2048LL * 256, 0, 0, 0, 128);
  // R1 = g1 @ [Kp1|Ke1] -> transposed rows [s1 logits^T | z1T]   (256^2 engine)
  mm256(stream, g1, KpKe1, R1, nullptr, 2048, 1280, 256, 256, 2048LL * 256, 0,
        SR1, SR1, 1);
  sm_partial_k<8><<<dim3(128, 8), dim3(256), 0, stream>>>(s1T, pm, ps, 1024, 2048, SR1, 128);
  sm_combine_k<<<dim3(8), dim3(256), 0, stream>>>(pm, ps, Mf, Sinv, 2048, 128);
  sm_norm_k<8><<<dim3(128, 8), dim3(256), 0, stream>>>(s1T, Mf, Sinv, 1024, 2048, SR1, 128);
  // AS1 dual: normal [2048][1024] + transposed into AS1T slot    (256^2 engine)
  mm256(stream, adjb, s1T, AS1, AS1T, 2048, 1024, 2048, 2048, 0, SR1,
        2048LL * 1024, SR1, 3);
  // P1 = s1^T @ [z1 | AS1] -> [xp1 | A1]  (M=1024,N=1280,K=2048) (256^2 engine)
  mm256(stream, s1T, B1, P1o, nullptr, 1024, 1280, 2048, 2048, SR1, SR1,
        1024LL * 1280, 0, 0);
  mm(stream, P1o, We2T, nullptr, t1T, nullptr, 1024, 256, 256, 1280, 1024LL * 1280,
     0, 0, 256LL * 1024, 0, 1, 128);
  mm(stream, A1c, t1T, be2, h2T, nullptr, 1024, 256, 1024, 1280, 1024LL * 1280,
     256LL * 1024, 0, 256LL * 1024, 1, 1, 128);
  mm(stream, A1c, h2T, nullptr, g2, nullptr, 1024, 256, 1024, 1280, 1024LL * 1280,
     256LL * 1024, 1024LL * 256, 0, 0, 0, 128);
  mm(stream, g2, KpKe2, nullptr, R2, nullptr, 1024, 768, 256, 256, 1024LL * 256,
     0, 0, SR2, 0, 1, 128);  // rows 0-511: s2 logits^T, 512-767: z2T
  sm_partial_k<4><<<dim3(64, 8), dim3(256), 0, stream>>>(s2T, pm, ps, 512, 1024, SR2, 64);
  sm_combine_k<<<dim3(8), dim3(256), 0, stream>>>(pm, ps, Mf, Sinv, 1024, 128);
  sm_norm_k<4><<<dim3(64, 8), dim3(256), 0, stream>>>(s2T, Mf, Sinv, 512, 1024, SR2, 64);
  mm(stream, A1c, s2T, nullptr, AS2, AS2T, 1024, 512, 1024, 1280, 1024LL * 1280,
     SR2, 1024LL * 512, SR2, 0, 3, 128);
  // P2 = s2^T @ [z2 | AS2]  ->  [xp2 | A2]   (M=512, N=768, K=1024)
  mm(stream, s2T, B2, nullptr, P2o, nullptr, 512, 768, 1024, 1024, SR2, SR2,
     512LL * 768, 0, 0, 0, 128);
  mm(stream, P2o, We3T, nullptr, t2T, nullptr, 512, 128, 256, 768, 512LL * 768,
     0, 0, 128LL * 512, 0, 1, 128);
  mm(stream, A2c, t2T, be3, h3f, nullptr, 512, 128, 512, 768, 512LL * 768,
     128LL * 512, 512LL * 128, 0, 0, 2, 128);
  reparam_k<<<dim3(8 * 512 * 64 / 256), dim3(256), 0, stream>>>(h3f, eps, out_mean,
                                                                out_lv, zlb, 8 * 512 * 64);

  // ---------------- decode ----------------
  mm(stream, zlb, Wd0T, nullptr, t3T, nullptr, 512, 256, 64, 64, 512LL * 64, 0, 0,
     256LL * 512, 0, 1, 128);
  mm(stream, A2c, t3T, bd0, d0, nullptr, 512, 256, 512, 768, 512LL * 768,
     256LL * 512, 512LL * 256, 0, 1, 0, 128);
  mm(stream, d0, Wd1T, nullptr, t4T, nullptr, 512, 256, 256, 256, 512LL * 256, 0,
     0, 256LL * 512, 0, 1, 128);
  mm(stream, AS2, t4T, bd1, d2, nullptr, 1024, 256, 512, 512, 1024LL * 512,
     256LL * 512, 1024LL * 256, 0, 1, 0, 128);
  mm(stream, d2, Wd2T, nullptr, t5T, nullptr, 1024, 256, 256, 256, 1024LL * 256, 0,
     0, 256LL * 1024, 0, 1, 128);
  mm(stream, AS1, t5T, bd2, d4, nullptr, 2048, 256, 1024, 1024, 2048LL * 1024,
     256LL * 1024, 2048LL * 256, 0, 1, 0, 128);
  mm(stream, d4, WdfT, nullptr, t6T, nullptr, 2048, 64, 256, 256, 2048LL * 256, 0,
     0, 64LL * 2048, 0, 1, 64);
  mm(stream, adjb, t6T, bdf, out, nullptr, 2048, 64, 2048, 2048, 0, 64LL * 2048,
     2048LL * 64, 0, 2, 2, 64);
}

// Round 7
// 664.394 us; speedup vs baseline: 1.1663x; 1.1663x over previous
//
#include <hip/hip_runtime.h>
#include <math.h>

#define BATCH 8
typedef unsigned short US;

typedef __attribute__((ext_vector_type(8))) short short8;
typedef __attribute__((ext_vector_type(4))) float f32x4;

__device__ __forceinline__ US f2b(float f) {
  union { float f; unsigned u; } v; v.f = f;
  unsigned r = v.u + 0x7fffu + ((v.u >> 16) & 1u);
  return (US)(r >> 16);
}
__device__ __forceinline__ float b2f(US h) {
  union { unsigned u; float f; } v; v.u = ((unsigned)h) << 16;
  return v.f;
}

__device__ __forceinline__ void gload16(const US* g, US* l) {
  __builtin_amdgcn_global_load_lds(
      (const __attribute__((address_space(1))) unsigned int*)g,
      (__attribute__((address_space(3))) unsigned int*)l, 16, 0, 0);
}

// LDS tile [rows][64] linear, XOR swizzle: 16B-cell index ^= (row&7).
__device__ __forceinline__ int lidx2(int r, int ko) {
  return r * 64 + ((((ko >> 3) ^ (r & 7)) << 3));
}

// ================= 128^2 1-phase MFMA GEMM (verified r3-r5) ==================
// C = act(A@B + bias). A bf16 phys [M][lda], B bf16 phys [N][K].
// OUT: 0=bf16 [M][N], 1=bf16 [N][M], 2=f32 [M][N], 3=dual bf16 [M][N]+[N][M].
template <int TN, int ACT, int OUT, bool HASBIAS>
__global__ __launch_bounds__(256) void mm_k(
    const US* __restrict__ A, const US* __restrict__ B,
    const float* __restrict__ bias, void* __restrict__ Cv, void* __restrict__ Cv2,
    int M, int N, int K, int lda, long long sA, long long sB, long long sC,
    long long sC2, int gx, int gy) {
  constexpr int JF = TN / 32;
  __shared__ US As[128 * 64];
  __shared__ US Bs[TN * 64];

  const int nb = blockIdx.x;
  const int nb2 = (nb & 7) * (gx * gy) + (nb >> 3);
  const int bx = nb2 % gx;
  const int by = (nb2 / gx) % gy;
  const int b = nb2 / (gx * gy);

  A += (long long)b * sA;
  B += (long long)b * sB;
  const int m0 = by * 128, n0 = bx * TN;
  const int t = threadIdx.x, lane = t & 63, w = t >> 6;
  const int wm = (w >> 1) * 64, wn = (w & 1) * (TN / 2);
  const int l15 = lane & 15, lg = lane >> 4;
  const int lrow = lane >> 3;
  const int gcell = (((lane & 7) ^ lrow) << 3);

  f32x4 acc[4][JF];
#pragma unroll
  for (int i = 0; i < 4; ++i)
#pragma unroll
    for (int j = 0; j < JF; ++j) acc[i][j] = (f32x4){0.f, 0.f, 0.f, 0.f};

  for (int k0 = 0; k0 < K; k0 += 64) {
#pragma unroll
    for (int i = 0; i < 4; ++i) {
      const int g = w * 4 + i;
      gload16(A + (long long)(m0 + g * 8 + lrow) * lda + k0 + gcell, &As[g * 512]);
    }
#pragma unroll
    for (int i = 0; i < TN / 32; ++i) {
      const int g = w * (TN / 32) + i;
      gload16(B + (long long)(n0 + g * 8 + lrow) * K + k0 + gcell, &Bs[g * 512]);
    }
    __syncthreads();

#pragma unroll
    for (int kk = 0; kk < 2; ++kk) {
      const int ko = kk * 32 + lg * 8;
      short8 af[4], bf[JF];
#pragma unroll
      for (int i = 0; i < 4; ++i)
        af[i] = *(const short8*)&As[lidx2(wm + i * 16 + l15, ko)];
#pragma unroll
      for (int j = 0; j < JF; ++j)
        bf[j] = *(const short8*)&Bs[lidx2(wn + j * 16 + l15, ko)];
#pragma unroll
      for (int i = 0; i < 4; ++i)
#pragma unroll
        for (int j = 0; j < JF; ++j)
          acc[i][j] = __builtin_amdgcn_mfma_f32_16x16x32_bf16(af[i], bf[j],
                                                              acc[i][j], 0, 0, 0);
    }
    __syncthreads();
  }

  const long long cb = (long long)b * sC;
  const long long cb2 = (long long)b * sC2;
#pragma unroll
  for (int fj = 0; fj < JF; ++fj) {
    const int col = n0 + wn + fj * 16 + l15;
    const float bsv = HASBIAS ? bias[col] : 0.0f;
#pragma unroll
    for (int fi = 0; fi < 4; ++fi) {
      const int row0 = m0 + wm + fi * 16 + lg * 4;
      float v[4];
#pragma unroll
      for (int e = 0; e < 4; ++e) {
        float x = acc[fi][fj][e] + bsv;
        if (ACT == 1) x = fmaxf(x, 0.0f);
        if (ACT == 2) x = (x > 20.0f) ? x : log1pf(expf(x));
        v[e] = x;
      }
      if (OUT == 1 || OUT == 3) {
        ushort4 pk;
        pk.x = f2b(v[0]); pk.y = f2b(v[1]); pk.z = f2b(v[2]); pk.w = f2b(v[3]);
        US* c2 = (OUT == 3) ? (US*)Cv2 : (US*)Cv;
        *(ushort4*)&c2[cb2 + (long long)col * M + row0] = pk;
      }
      if (OUT == 0 || OUT == 3) {
#pragma unroll
        for (int e = 0; e < 4; ++e)
          ((US*)Cv)[cb + (long long)(row0 + e) * N + col] = f2b(v[e]);
      }
      if (OUT == 2) {
#pragma unroll
        for (int e = 0; e < 4; ++e)
          ((float*)Cv)[cb + (long long)(row0 + e) * N + col] = v[e];
      }
    }
  }
}

// ================= 256^2 8-phase deep-pipelined MFMA GEMM ====================
// A bf16 [M][lda], B bf16 [N][K]. M%256==0, N%256==0, K%64==0, K>=192.
// Phases per K-tile: (kk0,mh0)(kk0,mh1)(kk1,mh0)(kk1,mh1); B-frags cached over
// the mh pair. One vmcnt per tile (phase 3): vmcnt(4) [H=4t+8,4t+9 in flight],
// drain 0 at tile NT-2. Stage distance 6 half-tiles; 8 LDS regions
// [256r][32k], cell swizzle c ^= (r>>1)&3 via pre-swizzled global source.
template <int OUT>
__global__ __launch_bounds__(512, 1) void mm256_k(
    const US* __restrict__ A, const US* __restrict__ B, void* __restrict__ Cv,
    void* __restrict__ Cv2, int M, int N, int K, int lda, long long sA,
    long long sB, long long sC, long long sC2, int gx, int gy) {
  __shared__ US lds[8][8192];

  const int nb = blockIdx.x;
  const int chunk = gx * gy;
  const int nb2 = (nb & 7) * chunk + (nb >> 3);
  const int bx = nb2 % gx;
  const int by = (nb2 / gx) % gy;
  const int b = nb2 / chunk;

  const int m0 = by * 256, n0 = bx * 256;
  const int tid = threadIdx.x;
  const int lane = tid & 63, w = tid >> 6;
  const int wr = w >> 2, wc = w & 3;      // 2 x 4 wave grid
  const int l15 = lane & 15, lg = lane >> 4;

  const US* Ab = A + (long long)b * sA + (long long)m0 * lda;
  const US* Bb = B + (long long)b * sB + (long long)n0 * K;
  const int NT = K >> 6;

  auto stageH = [&](int H) {
    const int s = H >> 2, h = H & 3;
    const int ab = h & 1, kk = h >> 1;
    US* reg = &lds[ab * 4 + (s & 1) * 2 + kk][0];
    const US* src = ab ? Bb : Ab;
    const int ld = ab ? K : lda;
#pragma unroll
    for (int i = 0; i < 2; ++i) {
      const int rbase = (w * 2 + i) * 16;
      const int r = rbase + (lane >> 2);
      const int csrc = (lane & 3) ^ ((r >> 1) & 3);
      gload16(src + (long long)r * ld + s * 64 + kk * 32 + csrc * 8,
              reg + rbase * 32);
    }
  };

  f32x4 acc[8][4];
#pragma unroll
  for (int m = 0; m < 8; ++m)
#pragma unroll
    for (int j = 0; j < 4; ++j) acc[m][j] = (f32x4){0.f, 0.f, 0.f, 0.f};
  short8 a4[4], b4[4];

  // prologue: H0..H5 (12 loads); wait until H0..H3 (tile 0) landed
  for (int H = 0; H < 6; ++H) stageH(H);
  asm volatile("s_waitcnt vmcnt(4)" ::: "memory");
  __builtin_amdgcn_s_barrier();

// VM: 0 none, 1 vmcnt(4), 2 vmcnt(0)
#define PH(kk_, mh_, DOH, HV, VM, tt)                                          \
  {                                                                            \
    const US* Ar = &lds[((tt) & 1) * 2 + (kk_)][0];                            \
    const US* Br = &lds[4 + ((tt) & 1) * 2 + (kk_)][0];                        \
    _Pragma("unroll") for (int i = 0; i < 4; ++i) {                            \
      const int r = wr * 128 + (mh_) * 64 + i * 16 + l15;                      \
      a4[i] = *(const short8*)&Ar[r * 32 + ((lg ^ ((r >> 1) & 3)) << 3)];      \
    }                                                                          \
    if ((mh_) == 0) {                                                          \
      _Pragma("unroll") for (int j = 0; j < 4; ++j) {                          \
        const int rr = wc * 64 + j * 16 + l15;                                 \
        b4[j] = *(const short8*)&Br[rr * 32 + ((lg ^ ((rr >> 1) & 3)) << 3)];  \
      }                                                                        \
    }                                                                          \
    if (DOH) stageH(HV);                                                       \
    if ((VM) == 1) asm volatile("s_waitcnt vmcnt(4)" ::: "memory");            \
    if ((VM) == 2) asm volatile("s_waitcnt vmcnt(0)" ::: "memory");            \
    __builtin_amdgcn_s_barrier();                                              \
    __builtin_amdgcn_s_setprio(1);                                             \
    _Pragma("unroll") for (int i = 0; i < 4; ++i)                              \
      _Pragma("unroll") for (int j = 0; j < 4; ++j)                            \
        acc[(mh_) * 4 + i][j] = __builtin_amdgcn_mfma_f32_16x16x32_bf16(       \
            a4[i], b4[j], acc[(mh_) * 4 + i][j], 0, 0, 0);                     \
    __builtin_amdgcn_s_setprio(0);                                             \
    __builtin_amdgcn_s_barrier();                                              \
  }

  int t2 = 0;
  for (; t2 < NT - 2; ++t2) {
    PH(0, 0, true, 4 * t2 + 6, 0, t2)
    PH(0, 1, true, 4 * t2 + 7, 0, t2)
    PH(1, 0, true, 4 * t2 + 8, 0, t2)
    PH(1, 1, true, 4 * t2 + 9, 1, t2)
  }
  // tile NT-2: only first two stages valid; drain to 0 for the last tile
  PH(0, 0, true, 4 * (NT - 2) + 6, 0, NT - 2)
  PH(0, 1, true, 4 * (NT - 2) + 7, 0, NT - 2)
  PH(1, 0, false, 0, 0, NT - 2)
  PH(1, 1, false, 0, 2, NT - 2)
  // tile NT-1: no staging, no waits
  PH(0, 0, false, 0, 0, NT - 1)
  PH(0, 1, false, 0, 0, NT - 1)
  PH(1, 0, false, 0, 0, NT - 1)
  PH(1, 1, false, 0, 0, NT - 1)
#undef PH

  const long long cb = (long long)b * sC;
  const long long cb2 = (long long)b * sC2;
#pragma unroll
  for (int j = 0; j < 4; ++j) {
    const int col = n0 + wc * 64 + j * 16 + l15;
#pragma unroll
    for (int m = 0; m < 8; ++m) {
      const int row0 = m0 + wr * 128 + m * 16 + lg * 4;
      if (OUT == 1 || OUT == 3) {
        ushort4 pk;
        pk.x = f2b(acc[m][j][0]); pk.y = f2b(acc[m][j][1]);
        pk.z = f2b(acc[m][j][2]); pk.w = f2b(acc[m][j][3]);
        US* c2 = (OUT == 3) ? (US*)Cv2 : (US*)Cv;
        *(ushort4*)&c2[cb2 + (long long)col * M + row0] = pk;
      }
      if (OUT == 0 || OUT == 3) {
#pragma unroll
        for (int e = 0; e < 4; ++e)
          ((US*)Cv)[cb + (long long)(row0 + e) * N + col] = f2b(acc[m][j][e]);
      }
    }
  }
}

// ================= 64x64 4-deep pipelined MFMA GEMM (skinny N) ===============
// A bf16 [M][lda], B bf16 [N][K]. M%64==0, N%64==0, K%64==0, K>=256.
// 4 waves (2x2), per-wave 32x32 out. 4 LDS buffers, stage distance 3,
// counted vmcnt(12/8/4/0). OUT: 0=bf16 [M][N], 1=bf16 [N][M], 2=f32 [M][N].
template <int ACT, int OUT, bool HASBIAS>
__global__ __launch_bounds__(256) void mm64_k(
    const US* __restrict__ A, const US* __restrict__ B,
    const float* __restrict__ bias, void* __restrict__ Cv,
    int M, int N, int K, int lda, long long sA, long long sB, long long sC,
    int gx, int gy) {
  __shared__ US As[4][4096];
  __shared__ US Bs[4][4096];

  const int nb = blockIdx.x;
  const int chunk = gx * gy;
  const int nb2 = (nb & 7) * chunk + (nb >> 3);
  const int bx = nb2 % gx;
  const int by = (nb2 / gx) % gy;
  const int b = nb2 / chunk;

  const int m0 = by * 64, n0 = bx * 64;
  const int tid = threadIdx.x;
  const int lane = tid & 63, w = tid >> 6;
  const int wr = w >> 1, wc = w & 1;
  const int l15 = lane & 15, lg = lane >> 4;
  const int lrow = lane >> 3;
  const int gcell = (((lane & 7) ^ lrow) << 3);

  const US* Ag = A + (long long)b * sA + (long long)m0 * lda;
  const US* Bg = B + (long long)b * sB + (long long)n0 * K;
  const int NT = K >> 6;

  auto stage = [&](int tt) {
    US* Ad = &As[tt & 3][0];
    US* Bd = &Bs[tt & 3][0];
    const int k0 = tt * 64;
#pragma unroll
    for (int i = 0; i < 2; ++i) {
      const int g = w * 2 + i;
      const int r = g * 8 + lrow;
      gload16(Ag + (long long)r * lda + k0 + gcell, Ad + g * 512);
      gload16(Bg + (long long)r * K + k0 + gcell, Bd + g * 512);
    }
  };

  f32x4 acc[2][2];
#pragma unroll
  for (int i = 0; i < 2; ++i)
#pragma unroll
    for (int j = 0; j < 2; ++j) acc[i][j] = (f32x4){0.f, 0.f, 0.f, 0.f};

  for (int i = 0; i < 3 && i < NT; ++i) stage(i);

  for (int t = 0; t < NT; ++t) {
    if (t + 3 < NT) stage(t + 3);
    const int rem = NT - 1 - t;
    if (rem >= 3) asm volatile("s_waitcnt vmcnt(12)" ::: "memory");
    else if (rem == 2) asm volatile("s_waitcnt vmcnt(8)" ::: "memory");
    else if (rem == 1) asm volatile("s_waitcnt vmcnt(4)" ::: "memory");
    else asm volatile("s_waitcnt vmcnt(0)" ::: "memory");
    __builtin_amdgcn_s_barrier();
    const US* Ad = &As[t & 3][0];
    const US* Bd = &Bs[t & 3][0];
#pragma unroll
    for (int kk = 0; kk < 2; ++kk) {
      const int ko = kk * 32 + lg * 8;
      short8 af[2], bf[2];
      af[0] = *(const short8*)&Ad[lidx2(wr * 32 + l15, ko)];
      af[1] = *(const short8*)&Ad[lidx2(wr * 32 + 16 + l15, ko)];
      bf[0] = *(const short8*)&Bd[lidx2(wc * 32 + l15, ko)];
      bf[1] = *(const short8*)&Bd[lidx2(wc * 32 + 16 + l15, ko)];
#pragma unroll
      for (int i = 0; i < 2; ++i)
#pragma unroll
        for (int j = 0; j < 2; ++j)
          acc[i][j] = __builtin_amdgcn_mfma_f32_16x16x32_bf16(af[i], bf[j],
                                                              acc[i][j], 0, 0, 0);
    }
    __builtin_amdgcn_s_barrier();
  }

  const long long cb = (long long)b * sC;
#pragma unroll
  for (int fj = 0; fj < 2; ++fj) {
    const int col = n0 + wc * 32 + fj * 16 + l15;
    const float bsv = HASBIAS ? bias[col] : 0.0f;
#pragma unroll
    for (int fi = 0; fi < 2; ++fi) {
      const int row0 = m0 + wr * 32 + fi * 16 + lg * 4;
      float v[4];
#pragma unroll
      for (int e = 0; e < 4; ++e) {
        float x = acc[fi][fj][e] + bsv;
        if (ACT == 1) x = fmaxf(x, 0.0f);
        if (ACT == 2) x = (x > 20.0f) ? x : log1pf(expf(x));
        v[e] = x;
      }
      if (OUT == 1) {
        ushort4 pk;
        pk.x = f2b(v[0]); pk.y = f2b(v[1]); pk.z = f2b(v[2]); pk.w = f2b(v[3]);
        *(ushort4*)&((US*)Cv)[cb + (long long)col * M + row0] = pk;
      } else if (OUT == 0) {
#pragma unroll
        for (int e = 0; e < 4; ++e)
          ((US*)Cv)[cb + (long long)(row0 + e) * N + col] = f2b(v[e]);
      } else {
#pragma unroll
        for (int e = 0; e < 4; ++e)
          ((float*)Cv)[cb + (long long)(row0 + e) * N + col] = v[e];
      }
    }
  }
}

// ---------------- split column softmax over R of x [B][R][C] ----------------
template <int RPT>
__global__ __launch_bounds__(256) void sm_partial_k(
    const US* __restrict__ x, float* __restrict__ pm, float* __restrict__ ps,
    int R, int C, long long sB, int NS) {
  const int b = blockIdx.y, blk = blockIdx.x;
  const int cpr = C >> 3;
  const int t = threadIdx.x;
  const int cslot = t & (cpr - 1);
  const int rsub = t / cpr;
  const int nsub = 256 / cpr;
  const int rowsPerBlock = R / NS;
  const int r0 = blk * rowsPerBlock + rsub * RPT;
  const US* p = x + (long long)b * sB + (long long)r0 * C + cslot * 8;
  union { uint4 v; US s[8]; } buf[RPT];
#pragma unroll
  for (int i = 0; i < RPT; ++i) buf[i].v = *(const uint4*)(p + (long long)i * C);
  float M[8], S[8];
#pragma unroll
  for (int j = 0; j < 8; ++j) M[j] = b2f(buf[0].s[j]);
#pragma unroll
  for (int i = 1; i < RPT; ++i)
#pragma unroll
    for (int j = 0; j < 8; ++j) M[j] = fmaxf(M[j], b2f(buf[i].s[j]));
#pragma unroll
  for (int j = 0; j < 8; ++j) S[j] = 0.f;
#pragma unroll
  for (int i = 0; i < RPT; ++i)
#pragma unroll
    for (int j = 0; j < 8; ++j) S[j] += __expf(b2f(buf[i].s[j]) - M[j]);
  const long long pi = (long long)(b * NS + blk) * nsub + rsub;
  float* pmo = pm + pi * C + cslot * 8;
  float* pso = ps + pi * C + cslot * 8;
  *(float4*)pmo = make_float4(M[0], M[1], M[2], M[3]);
  *(float4*)(pmo + 4) = make_float4(M[4], M[5], M[6], M[7]);
  *(float4*)pso = make_float4(S[0], S[1], S[2], S[3]);
  *(float4*)(pso + 4) = make_float4(S[4], S[5], S[6], S[7]);
}

__global__ __launch_bounds__(256) void sm_combine_k(
    const float* __restrict__ pm, const float* __restrict__ ps,
    float* __restrict__ Mf, float* __restrict__ Sinv, int C, int NP) {
  const int b = blockIdx.x, t = threadIdx.x;
  const int cpr = C >> 3;
  if (t >= cpr) return;
  const int c = t * 8;
  const float* pmB = pm + (long long)b * NP * C + c;
  const float* psB = ps + (long long)b * NP * C + c;
  float M[8], S[8];
#pragma unroll
  for (int j = 0; j < 8; ++j) { M[j] = pmB[j]; S[j] = psB[j]; }
  for (int e = 1; e < NP; ++e) {
    const float* pme = pmB + (long long)e * C;
    const float* pse = psB + (long long)e * C;
#pragma unroll
    for (int j = 0; j < 8; ++j) {
      const float m2 = pme[j], s2 = pse[j];
      const float nm = fmaxf(M[j], m2);
      S[j] = S[j] * __expf(M[j] - nm) + s2 * __expf(m2 - nm);
      M[j] = nm;
    }
  }
#pragma unroll
  for (int j = 0; j < 8; ++j) {
    Mf[(long long)b * C + c + j] = M[j];
    Sinv[(long long)b * C + c + j] = 1.0f / S[j];
  }
}

template <int RPT>
__global__ __launch_bounds__(256) void sm_norm_k(
    US* __restrict__ x, const float* __restrict__ Mf,
    const float* __restrict__ Sinv, int R, int C, long long sB, int NS) {
  const int b = blockIdx.y, blk = blockIdx.x;
  const int cpr = C >> 3;
  const int t = threadIdx.x;
  const int cslot = t & (cpr - 1);
  const int rsub = t / cpr;
  const int rowsPerBlock = R / NS;
  const int r0 = blk * rowsPerBlock + rsub * RPT;
  US* p = x + (long long)b * sB + (long long)r0 * C + cslot * 8;
  float M[8], Si[8];
#pragma unroll
  for (int j = 0; j < 8; ++j) {
    M[j] = Mf[(long long)b * C + cslot * 8 + j];
    Si[j] = Sinv[(long long)b * C + cslot * 8 + j];
  }
#pragma unroll
  for (int i = 0; i < RPT; ++i) {
    union { uint4 v; US s[8]; } buf;
    buf.v = *(const uint4*)(p + (long long)i * C);
#pragma unroll
    for (int j = 0; j < 8; ++j)
      buf.s[j] = f2b(__expf(b2f(buf.s[j]) - M[j]) * Si[j]);
    *(uint4*)(p + (long long)i * C) = buf.v;
  }
}

// ---------------- f32 transpose -> bf16: [B][R][C] -> [B][C][R] ----
__global__ __launch_bounds__(256) void trans_k(const float* __restrict__ src,
                                               US* __restrict__ dst, int R, int C,
                                               long long sIn, long long sOut) {
  __shared__ US L[64][65];
  const int b = blockIdx.z;
  const int r0 = blockIdx.y * 64, c0 = blockIdx.x * 64;
  const int t = threadIdx.x;
  const int lr = t >> 4, lc = (t & 15) * 4;
  const float* s = src + (long long)b * sIn;
#pragma unroll
  for (int i = 0; i < 4; ++i) {
    const int rr = r0 + lr + 16 * i;
    const float4 v = *(const float4*)&s[(long long)rr * C + c0 + lc];
    L[lr + 16 * i][lc + 0] = f2b(v.x);
    L[lr + 16 * i][lc + 1] = f2b(v.y);
    L[lr + 16 * i][lc + 2] = f2b(v.z);
    L[lr + 16 * i][lc + 3] = f2b(v.w);
  }
  __syncthreads();
#pragma unroll
  for (int i = 0; i < 4; ++i) {
    ushort4 o;
    o.x = L[lc + 0][lr + 16 * i];
    o.y = L[lc + 1][lr + 16 * i];
    o.z = L[lc + 2][lr + 16 * i];
    o.w = L[lc + 3][lr + 16 * i];
    *(ushort4*)&dst[(long long)b * sOut + (long long)(c0 + lr + 16 * i) * R + r0 + lc] = o;
  }
}

// ---------------- fused weight transposes ----------------
struct WT { const float* src; US* dst; int R, C, tileOff; };
struct WTab { WT e[11]; };

__global__ __launch_bounds__(256) void wtrans_k(WTab tab) {
  __shared__ US L[64][65];
  const int tile = blockIdx.x;
  int i = 0;
#pragma unroll
  for (int j = 1; j < 11; ++j)
    if (tab.e[j].tileOff <= tile) i = j;
  const WT w = tab.e[i];
  const int lt = tile - w.tileOff;
  const int tc = w.C / 64;
  const int r0 = (lt / tc) * 64, c0 = (lt % tc) * 64;
  const int t = threadIdx.x;
  const int lr = t >> 4, lc = (t & 15) * 4;
#pragma unroll
  for (int k = 0; k < 4; ++k) {
    const int rr = r0 + lr + 16 * k;
    const float4 v = *(const float4*)&w.src[(long long)rr * w.C + c0 + lc];
    L[lr + 16 * k][lc + 0] = f2b(v.x);
    L[lr + 16 * k][lc + 1] = f2b(v.y);
    L[lr + 16 * k][lc + 2] = f2b(v.z);
    L[lr + 16 * k][lc + 3] = f2b(v.w);
  }
  __syncthreads();
#pragma unroll
  for (int k = 0; k < 4; ++k) {
    ushort4 o;
    o.x = L[lc + 0][lr + 16 * k];
    o.y = L[lc + 1][lr + 16 * k];
    o.z = L[lc + 2][lr + 16 * k];
    o.w = L[lc + 3][lr + 16 * k];
    *(ushort4*)&w.dst[(long long)(c0 + lr + 16 * k) * w.R + r0 + lc] = o;
  }
}

// ---------------- f32 -> bf16 ----------------
__global__ __launch_bounds__(256) void f2b_k(const float* __restrict__ s,
                                             US* __restrict__ d, int n4) {
  const int i = blockIdx.x * 256 + threadIdx.x;
  if (i < n4) {
    const float4 v = ((const float4*)s)[i];
    ushort4 o;
    o.x = f2b(v.x); o.y = f2b(v.y); o.z = f2b(v.z); o.w = f2b(v.w);
    ((ushort4*)d)[i] = o;
  }
}

// ---------------- reparameterize ----------------
__global__ __launch_bounds__(256) void reparam_k(
    const float* __restrict__ h3, const float* __restrict__ eps,
    float* __restrict__ om, float* __restrict__ olv, US* __restrict__ z,
    int total) {
  const int i = blockIdx.x * 256 + threadIdx.x;
  if (i >= total) return;
  const int j = i & 63;
  const long long r = i >> 6;
  const float m = h3[r * 128 + j];
  const float lv = h3[r * 128 + 64 + j];
  om[i] = m;
  olv[i] = lv;
  z[i] = f2b(m + expf(0.5f * lv) * eps[i]);
}

// ---------------- host dispatch ----------------
static void mm(hipStream_t st, const US* A, const US* B, const float* bias,
               void* C, void* C2, int M, int N, int K, int lda, long long sA,
               long long sB, long long sC, long long sC2, int act, int outm,
               int tn) {
  const int gx = N / tn, gy = M / 128;
  dim3 g(gx * gy * BATCH), blk(256);
#define L(TN, ACT, OUT, HB) \
  mm_k<TN, ACT, OUT, HB><<<g, blk, 0, st>>>(A, B, bias, C, C2, M, N, K, lda, sA, sB, sC, sC2, gx, gy)
  if (tn == 64) {
    if (outm == 0) L(64, 0, 0, false);
    else if (outm == 1) L(64, 0, 1, false);
    else L(64, 2, 2, true);
  } else {
    if (outm == 0) {
      if (act == 1) L(128, 1, 0, true);
      else L(128, 0, 0, false);
    } else if (outm == 1) {
      if (act == 1) L(128, 1, 1, true);
      else L(128, 0, 1, false);
    } else if (outm == 2) L(128, 0, 2, true);
    else L(128, 0, 3, false);
  }
#undef L
}

static void mm256(hipStream_t st, const US* A, const US* B, void* C, void* C2,
                  int M, int N, int K, int lda, long long sA, long long sB,
                  long long sC, long long sC2, int outm) {
  const int gx = N / 256, gy = M / 256;
  dim3 g(gx * gy * BATCH), blk(512);
  if (outm == 0)
    mm256_k<0><<<g, blk, 0, st>>>(A, B, C, C2, M, N, K, lda, sA, sB, sC, sC2, gx, gy);
  else if (outm == 1)
    mm256_k<1><<<g, blk, 0, st>>>(A, B, C, C2, M, N, K, lda, sA, sB, sC, sC2, gx, gy);
  else
    mm256_k<3><<<g, blk, 0, st>>>(A, B, C, C2, M, N, K, lda, sA, sB, sC, sC2, gx, gy);
}

static void mm64(hipStream_t st, const US* A, const US* B, const float* bias,
                 void* C, int M, int N, int K, int lda, long long sA,
                 long long sB, long long sC, int act, int outm) {
  const int gx = N / 64, gy = M / 64;
  dim3 g(gx * gy * BATCH), blk(256);
  if (outm == 0)
    mm64_k<0, 0, false><<<g, blk, 0, st>>>(A, B, nullptr, C, M, N, K, lda, sA, sB, sC, gx, gy);
  else if (outm == 1)
    mm64_k<0, 1, false><<<g, blk, 0, st>>>(A, B, nullptr, C, M, N, K, lda, sA, sB, sC, gx, gy);
  else
    mm64_k<2, 2, true><<<g, blk, 0, st>>>(A, B, bias, C, M, N, K, lda, sA, sB, sC, gx, gy);
}

extern "C" void kernel_launch(void* const* d_in, const int* in_sizes, int n_in,
                              void* d_out, int out_size, void* d_ws, size_t ws_size,
                              hipStream_t stream) {
  const float* x      = (const float*)d_in[0];
  const float* eps    = (const float*)d_in[1];
  const float* adj    = (const float*)d_in[2];
  const float* We1    = (const float*)d_in[3];
  const float* be1    = (const float*)d_in[4];
  const float* Kemb1  = (const float*)d_in[5];
  const float* Kpool1 = (const float*)d_in[6];
  const float* We2    = (const float*)d_in[7];
  const float* be2    = (const float*)d_in[8];
  const float* Kemb2  = (const float*)d_in[9];
  const float* Kpool2 = (const float*)d_in[10];
  const float* We3    = (const float*)d_in[11];
  const float* be3    = (const float*)d_in[12];
  const float* Wd0    = (const float*)d_in[13];
  const float* bd0    = (const float*)d_in[14];
  const float* Wd1    = (const float*)d_in[15];
  const float* bd1    = (const float*)d_in[16];
  const float* Wd2    = (const float*)d_in[17];
  const float* bd2    = (const float*)d_in[18];
  const float* Wdf    = (const float*)d_in[19];
  const float* bdf    = (const float*)d_in[20];
  (void)in_sizes; (void)n_in; (void)ws_size; (void)out_size;

  float* out = (float*)d_out;
  float* out_mean = out + (long long)8 * 2048 * 64;
  float* out_lv = out_mean + (long long)8 * 512 * 64;

  char* base = (char*)d_ws;
  size_t off = 0;
  auto alloc = [&](size_t bytes) {
    char* p = base + off;
    off += (bytes + 255) & ~(size_t)255;
    return p;
  };
  US* adjb = (US*)alloc(2048LL * 2048 * 2);
  US* xT   = (US*)alloc(8LL * 64 * 2048 * 2);
  US* Y0   = (US*)alloc(8LL * 2048 * 64 * 2);
  US* h1T  = (US*)alloc(8LL * 256 * 2048 * 2);
  US* g1   = (US*)alloc(8LL * 2048 * 256 * 2);
  US* R1   = (US*)alloc(8LL * 2304 * 2048 * 2);
  US* AS1  = (US*)alloc(8LL * 2048 * 1024 * 2);
  US* P1o  = (US*)alloc(8LL * 1024 * 1280 * 2);
  US* t1T  = (US*)alloc(8LL * 256 * 1024 * 2);
  US* h2T  = (US*)alloc(8LL * 256 * 1024 * 2);
  US* g2   = (US*)alloc(8LL * 1024 * 256 * 2);
  US* R2   = (US*)alloc(8LL * 1280 * 1024 * 2);
  US* AS2  = (US*)alloc(8LL * 1024 * 512 * 2);
  US* P2o  = (US*)alloc(8LL * 512 * 768 * 2);
  US* t2T  = (US*)alloc(8LL * 128 * 512 * 2);
  float* h3f = (float*)alloc(8LL * 512 * 128 * 4);
  US* zlb  = (US*)alloc(8LL * 512 * 64 * 2);
  US* t3T  = (US*)alloc(8LL * 256 * 512 * 2);
  US* d0   = (US*)alloc(8LL * 512 * 256 * 2);
  US* t4T  = (US*)alloc(8LL * 256 * 512 * 2);
  US* d2   = (US*)alloc(8LL * 1024 * 256 * 2);
  US* t5T  = (US*)alloc(8LL * 256 * 1024 * 2);
  US* d4   = (US*)alloc(8LL * 2048 * 256 * 2);
  US* t6T  = (US*)alloc(8LL * 64 * 2048 * 2);
  float* pm   = (float*)alloc(8LL * 128 * 2048 * 4);
  float* ps   = (float*)alloc(8LL * 128 * 2048 * 4);
  float* Mf   = (float*)alloc(8LL * 2048 * 4);
  float* Sinv = (float*)alloc(8LL * 2048 * 4);
  US* We1T  = (US*)alloc(256 * 64 * 2);
  US* KpKe1 = (US*)alloc(1280 * 256 * 2);
  US* We2T  = (US*)alloc(256 * 256 * 2);
  US* KpKe2 = (US*)alloc(768 * 256 * 2);
  US* We3T  = (US*)alloc(128 * 256 * 2);
  US* Wd0T  = (US*)alloc(256 * 64 * 2);
  US* Wd1T  = (US*)alloc(256 * 256 * 2);
  US* Wd2T  = (US*)alloc(256 * 256 * 2);
  US* WdfT  = (US*)alloc(64 * 256 * 2);

  // ---- input conversions ----
  f2b_k<<<dim3(2048 * 2048 / 4 / 256), dim3(256), 0, stream>>>(adj, adjb, 2048 * 2048 / 4);
  trans_k<<<dim3(1, 32, 8), dim3(256), 0, stream>>>(x, xT, 2048, 64, 2048LL * 64,
                                                    64LL * 2048);
  {
    WTab tab;
    int toff = 0, i = 0;
    auto add = [&](const float* s, US* d, int R, int C) {
      tab.e[i++] = WT{s, d, R, C, toff};
      toff += (R / 64) * (C / 64);
    };
    add(We1, We1T, 64, 256);
    add(Kpool1, KpKe1, 256, 1024);
    add(Kemb1, KpKe1 + 1024 * 256, 256, 256);
    add(We2, We2T, 256, 256);
    add(Kpool2, KpKe2, 256, 512);
    add(Kemb2, KpKe2 + 512 * 256, 256, 256);
    add(We3, We3T, 256, 128);
    add(Wd0, Wd0T, 64, 256);
    add(Wd1, Wd1T, 256, 256);
    add(Wd2, Wd2T, 256, 256);
    add(Wdf, WdfT, 256, 64);
    wtrans_k<<<dim3(toff), dim3(256), 0, stream>>>(tab);
  }

  const long long SR1 = 2304LL * 2048, SR2 = 1280LL * 1024;
  US* s1T  = R1;
  US* B1   = R1 + 1024 * 2048;
  US* AS1T = R1 + 1280 * 2048;
  US* s2T  = R2;
  US* B2   = R2 + 512 * 1024;
  US* AS2T = R2 + 768 * 1024;
  US* A1c  = P1o + 256;
  US* A2c  = P2o + 256;

  // ---------------- encode ----------------
  mm64(stream, adjb, xT, nullptr, Y0, 2048, 64, 2048, 2048, 0, 64LL * 2048,
       2048LL * 64, 0, 0);
  mm(stream, Y0, We1T, be1, h1T, nullptr, 2048, 256, 64, 64, 2048LL * 64, 0, 0,
     256LL * 2048, 1, 1, 128);
  mm(stream, adjb, h1T, nullptr, g1, nullptr, 2048, 256, 2048, 2048, 0,
     256LL * 2048, 2048LL * 256, 0, 0, 0, 128);
  mm(stream, g1, KpKe1, nullptr, R1, nullptr, 2048, 1280, 256, 256, 2048LL * 256,
     0, 0, SR1, 0, 1, 128);
  sm_partial_k<8><<<dim3(128, 8), dim3(256), 0, stream>>>(s1T, pm, ps, 1024, 2048, SR1, 128);
  sm_combine_k<<<dim3(8), dim3(256), 0, stream>>>(pm, ps, Mf, Sinv, 2048, 128);
  sm_norm_k<8><<<dim3(128, 8), dim3(256), 0, stream>>>(s1T, Mf, Sinv, 1024, 2048, SR1, 128);
  mm256(stream, adjb, s1T, AS1, AS1T, 2048, 1024, 2048, 2048, 0, SR1,
        2048LL * 1024, SR1, 3);
  mm(stream, s1T, B1, nullptr, P1o, nullptr, 1024, 1280, 2048, 2048, SR1, SR1,
     1024LL * 1280, 0, 0, 0, 128);
  mm(stream, P1o, We2T, nullptr, t1T, nullptr, 1024, 256, 256, 1280, 1024LL * 1280,
     0, 0, 256LL * 1024, 0, 1, 128);
  mm(stream, A1c, t1T, be2, h2T, nullptr, 1024, 256, 1024, 1280, 1024LL * 1280,
     256LL * 1024, 0, 256LL * 1024, 1, 1, 128);
  mm(stream, A1c, h2T, nullptr, g2, nullptr, 1024, 256, 1024, 1280, 1024LL * 1280,
     256LL * 1024, 1024LL * 256, 0, 0, 0, 128);
  mm(stream, g2, KpKe2, nullptr, R2, nullptr, 1024, 768, 256, 256, 1024LL * 256,
     0, 0, SR2, 0, 1, 128);
  sm_partial_k<4><<<dim3(64, 8), dim3(256), 0, stream>>>(s2T, pm, ps, 512, 1024, SR2, 64);
  sm_combine_k<<<dim3(8), dim3(256), 0, stream>>>(pm, ps, Mf, Sinv, 1024, 128);
  sm_norm_k<4><<<dim3(64, 8), dim3(256), 0, stream>>>(s2T, Mf, Sinv, 512, 1024, SR2, 64);
  mm(stream, A1c, s2T, nullptr, AS2, AS2T, 1024, 512, 1024, 1280, 1024LL * 1280,
     SR2, 1024LL * 512, SR2, 0, 3, 128);
  mm(stream, s2T, B2, nullptr, P2o, nullptr, 512, 768, 1024, 1024, SR2, SR2,
     512LL * 768, 0, 0, 0, 128);
  mm(stream, P2o, We3T, nullptr, t2T, nullptr, 512, 128, 256, 768, 512LL * 768,
     0, 0, 128LL * 512, 0, 1, 128);
  mm(stream, A2c, t2T, be3, h3f, nullptr, 512, 128, 512, 768, 512LL * 768,
     128LL * 512, 512LL * 128, 0, 0, 2, 128);
  reparam_k<<<dim3(8 * 512 * 64 / 256), dim3(256), 0, stream>>>(h3f, eps, out_mean,
                                                                out_lv, zlb, 8 * 512 * 64);

  // ---------------- decode ----------------
  mm(stream, zlb, Wd0T, nullptr, t3T, nullptr, 512, 256, 64, 64, 512LL * 64, 0, 0,
     256LL * 512, 0, 1, 128);
  mm(stream, A2c, t3T, bd0, d0, nullptr, 512, 256, 512, 768, 512LL * 768,
     256LL * 512, 512LL * 256, 0, 1, 0, 128);
  mm(stream, d0, Wd1T, nullptr, t4T, nullptr, 512, 256, 256, 256, 512LL * 256, 0,
     0, 256LL * 512, 0, 1, 128);
  mm(stream, AS2, t4T, bd1, d2, nullptr, 1024, 256, 512, 512, 1024LL * 512,
     256LL * 512, 1024LL * 256, 0, 1, 0, 128);
  mm(stream, d2, Wd2T, nullptr, t5T, nullptr, 1024, 256, 256, 256, 1024LL * 256, 0,
     0, 256LL * 1024, 0, 1, 128);
  mm(stream, AS1, t5T, bd2, d4, nullptr, 2048, 256, 1024, 1024, 2048LL * 1024,
     256LL * 1024, 2048LL * 256, 0, 1, 0, 128);
  mm64(stream, d4, WdfT, nullptr, t6T, 2048, 64, 256, 256, 2048LL * 256, 0,
       64LL * 2048, 0, 1);
  mm64(stream, adjb, t6T, bdf, out, 2048, 64, 2048, 2048, 0, 64LL * 2048,
       2048LL * 64, 2, 2);
}